// Round 17
// baseline (795.793 us; speedup 1.0000x reference)
//
#include <hip/hip_runtime.h>
#include <math.h>

#define NN   100000
#define EE   800000
#define RR   6
#define BB   1000
#define HH   128
#define MM   (RR*NN)
#define NBPR ((NN + 255) >> 8)
#define NBK  (RR * NBPR)
#define CH   4096
#define CAP  4096     // fixed capacity per bucket in ebkt staging

static inline int ceil_div(int a, int b){ return (a+b-1)/b; }

typedef __attribute__((ext_vector_type(8))) short bf16x8;
typedef __attribute__((ext_vector_type(4))) short bf16x4;
typedef __attribute__((ext_vector_type(4))) float f32x4;

__device__ __forceinline__ unsigned fenc(float f){
  unsigned u = __float_as_uint(f);
  return (u & 0x80000000u) ? ~u : (u | 0x80000000u);
}
__device__ __forceinline__ float fdec(unsigned u){
  return __uint_as_float((u & 0x80000000u) ? (u & 0x7fffffffu) : ~u);
}
__device__ __forceinline__ unsigned short f2bf(float f){
  unsigned u = __float_as_uint(f);
  return (unsigned short)((u + 0x7fffu + ((u >> 16) & 1u)) >> 16);
}
__device__ __forceinline__ float bf2f(unsigned short h){
  return __uint_as_float(((unsigned)h) << 16);
}
__device__ __forceinline__ float wexp(float z){
  z = (z > 0.f) ? z : 0.2f*z;              // LeakyReLU(0.2)
  z = fminf(fmaxf(z, -60.f), 60.f);
  return __expf(z);
}

// ================= CSR build: fixed-capacity binning (proven r9) =================
__global__ void k_binscatter(const int* __restrict__ edges, int* __restrict__ bcur,
                             unsigned* __restrict__ ebkt)
{
  __shared__ int hist[NBPR];
  __shared__ int base[NBPR];
  int t = threadIdx.x;
  const int nch = (EE + CH - 1) / CH;
  int r = blockIdx.x / nch, c = blockIdx.x - r*nch;
  for (int i = t; i < NBPR; i += 256) hist[i] = 0;
  __syncthreads();
  const int* sptr = edges + (size_t)r*2*EE;
  const int* dptr = sptr + EE;
  int e0 = c*CH, e1 = min(EE, e0 + CH);
  for (int i = e0 + t; i < e1; i += 256)
    atomicAdd(&hist[dptr[i] >> 8], 1);
  __syncthreads();
  for (int i = t; i < NBPR; i += 256) {
    int h = hist[i];
    int gb = r*NBPR + i;
    base[i] = h ? (gb*CAP + atomicAdd(&bcur[gb], h)) : 0;
    hist[i] = 0;
  }
  __syncthreads();
  for (int i = e0 + t; i < e1; i += 256) {
    int dst = dptr[i];
    int b = dst >> 8;
    int slot = base[b] + atomicAdd(&hist[b], 1);
    ebkt[slot] = ((unsigned)sptr[i] << 8) | (unsigned)(dst & 255);
  }
}

__global__ void k_bscan(const int* __restrict__ bcur, int* __restrict__ boff,
                        int* __restrict__ off)
{
  __shared__ int sh[256];
  int t = threadIdx.x;
  int carry = 0;
  for (int c = 0; c < NBK; c += 256) {
    int idx = c + t;
    int v = (idx < NBK) ? bcur[idx] : 0;
    sh[t] = v;
    __syncthreads();
    for (int o = 1; o < 256; o <<= 1) {
      int add = (t >= o) ? sh[t-o] : 0;
      __syncthreads();
      sh[t] += add;
      __syncthreads();
    }
    int incl = sh[t];
    int tot  = sh[255];
    if (idx < NBK) boff[idx] = carry + incl - v;
    __syncthreads();
    carry += tot;
  }
  if (t == 0) { boff[NBK] = carry; off[MM] = carry; }
}

__global__ void k_bbuild(const unsigned* __restrict__ ebkt, const int* __restrict__ bcur,
                         const int* __restrict__ boff,
                         int* __restrict__ off, int* __restrict__ elist)
{
  __shared__ int cnt[256];
  __shared__ int sc[256];
  __shared__ int cur[256];
  int t = threadIdx.x;
  int bb = blockIdx.x;
  int e0r = bb*CAP, e1r = e0r + bcur[bb];
  int w0 = boff[bb];
  cnt[t] = 0;
  __syncthreads();
  for (int i = e0r + t; i < e1r; i += 256)
    atomicAdd(&cnt[ebkt[i] & 255u], 1);
  __syncthreads();
  sc[t] = cnt[t];
  __syncthreads();
  for (int o = 1; o < 256; o <<= 1) {
    int add = (t >= o) ? sc[t-o] : 0;
    __syncthreads();
    sc[t] += add;
    __syncthreads();
  }
  int excl = sc[t] - cnt[t];
  int r = bb / NBPR, b = bb - r*NBPR;
  int dst = b*256 + t;
  if (dst < NN) off[r*NN + dst] = w0 + excl;
  cur[t] = w0 + excl;
  __syncthreads();
  for (int i = e0r + t; i < e1r; i += 256) {
    unsigned w = ebkt[i];
    int slot = atomicAdd(&cur[w & 255u], 1);
    elist[slot] = (int)(w >> 8);
  }
}

// ================= feature prep (bf16 hi/lo planes, K padded 21->32) =================
__global__ void k_featprep(const float* __restrict__ x_all, const float* __restrict__ pos_table,
                           short* __restrict__ x0h, short* __restrict__ x0l)
{
  int gid = blockIdx.x*256 + threadIdx.x;
  if (gid >= NN*32) return;
  int nidx = gid >> 5, c = gid & 31;
  float v = 0.f;
  if (c < 13) {
    int scl = (c < 5) ? c : c + 1;
    v = x_all[nidx*14 + scl];
  } else if (c < 21) {
    int pi = (int)x_all[nidx*14 + 5];
    pi = pi < 0 ? 0 : (pi > 23 ? 23 : pi);
    v = pos_table[pi*8 + (c - 13)];
  }
  unsigned short h = f2bf(v);
  unsigned short l = f2bf(v - bf2f(h));
  x0h[gid] = (short)h;
  x0l[gid] = (short)l;
}

// ================= weight prep (layer-1, row-major [r][out][KP]) =================
template<int KP>
__global__ void k_wprep(const float* __restrict__ W, int K,
                        short* __restrict__ Wh, short* __restrict__ Wl)
{
  int gid = blockIdx.x*256 + threadIdx.x;
  if (gid >= RR*128*KP) return;
  int r = gid / (128*KP);
  int rem = gid - r*(128*KP);
  int nn = rem / KP, k = rem - nn*KP;
  float v = (k < K) ? W[((size_t)r*K + k)*128 + nn] : 0.f;
  unsigned short h = f2bf(v);
  unsigned short l = f2bf(v - bf2f(h));
  Wh[gid] = (short)h;
  Wl[gid] = (short)l;
}

// ================= weight prep (layer-2, MFMA fragment layout) =================
__global__ void k_wprep2(const float* __restrict__ W,
                         short* __restrict__ Wh, short* __restrict__ Wl)
{
  int gid = blockIdx.x*256 + threadIdx.x;
  if (gid >= RR*128*128) return;
  int r = gid / (128*128);
  int i = gid - r*(128*128);
  int kc = i >> 12;
  int lg = (i >> 10) & 3;
  int row = (i >> 3) & 127;
  int e = i & 7;
  int k = kc*32 + 16*(e >> 2) + 4*lg + (e & 3);
  float v = W[((size_t)r*128 + k)*128 + row];
  unsigned short h = f2bf(v);
  unsigned short l = f2bf(v - bf2f(h));
  Wh[gid] = (short)h;
  Wl[gid] = (short)l;
}

// ================= wa: precompute W_r @ a =================
template<int KP>
__global__ void k_wa(const float* __restrict__ W, const float* __restrict__ as,
                     const float* __restrict__ ad, int K, float* __restrict__ wa)
{
  int idx = blockIdx.x*256 + threadIdx.x;
  if (idx >= 12*KP) return;
  int rr = idx / KP, k = idx - rr*KP;
  int r = (rr < 6) ? rr : rr - 6;
  const float* a = ((rr < 6) ? as : ad) + (size_t)r*HH;
  float s = 0.f;
  if (k < K) {
    const float* wrow = W + ((size_t)r*K + k)*128;
    #pragma unroll 8
    for (int h = 0; h < 128; ++h) s = fmaf(wrow[h], a[h], s);
  }
  wa[idx] = s;
}

// ================= zsd layer-1: [12][N] from x0 hi/lo =================
__global__ void k_zsd32(const short* __restrict__ xh, const short* __restrict__ xl,
                        const float* __restrict__ wa, float* __restrict__ zsd, int n)
{
  __shared__ float w[12*32];
  int tid = threadIdx.x;
  for (int i = tid; i < 12*32; i += 256) w[i] = wa[i];
  __syncthreads();
  int g = blockIdx.x*256 + tid;
  if (g >= n) return;
  float v[32];
  #pragma unroll
  for (int c = 0; c < 4; ++c) {
    uint4 vh = *(const uint4*)(xh + (size_t)g*32 + c*8);
    uint4 vl = *(const uint4*)(xl + (size_t)g*32 + c*8);
    const unsigned short* hp = (const unsigned short*)&vh;
    const unsigned short* lp = (const unsigned short*)&vl;
    #pragma unroll
    for (int j = 0; j < 8; ++j) v[c*8+j] = bf2f(hp[j]) + bf2f(lp[j]);
  }
  #pragma unroll
  for (int rr = 0; rr < 12; ++rr) {
    float d = 0.f;
    #pragma unroll
    for (int k = 0; k < 32; ++k) d = fmaf(v[k], w[rr*32+k], d);
    zsd[(size_t)rr*n + g] = d;
  }
}

// ================= zsd layer-2: [12][N] from h1 bf16-only =================
__global__ void k_zsd128(const unsigned short* __restrict__ xh,
                         const float* __restrict__ wa, float* __restrict__ zsd, int n)
{
  __shared__ float w[12*128];
  int tid = threadIdx.x;
  for (int i = tid; i < 12*128; i += 256) w[i] = wa[i];
  __syncthreads();
  int gid = blockIdx.x*256 + tid;
  int g = gid >> 4, l = tid & 15;
  if (g >= n) return;
  uint4 vh = *(const uint4*)(xh + (size_t)g*128 + l*8);
  const unsigned short* hp = (const unsigned short*)&vh;
  float v[8];
  #pragma unroll
  for (int j = 0; j < 8; ++j) v[j] = bf2f(hp[j]);
  float dot[12];
  #pragma unroll
  for (int rr = 0; rr < 12; ++rr) {
    float p = 0.f;
    #pragma unroll
    for (int j = 0; j < 8; ++j) p = fmaf(v[j], w[rr*128 + l*8 + j], p);
    p += __shfl_xor(p, 1); p += __shfl_xor(p, 2);
    p += __shfl_xor(p, 4); p += __shfl_xor(p, 8);
    dot[rr] = p;
  }
  if (l < 12) zsd[(size_t)l*n + g] = dot[l];
}

// ================= layer-1 aggregation: ONE-PASS, bf16-only output (proven r14) ======
__global__ void k_agg1(const unsigned short* __restrict__ x0h, const float* __restrict__ zsd,
                       const int* __restrict__ elist, const int* __restrict__ off,
                       unsigned short* __restrict__ aggH, int n)
{
  int gid = blockIdx.x*256 + threadIdx.x;
  int g = gid >> 4;
  int l = threadIdx.x & 15;
  if (g >= n) return;
  int sub = l >> 2, ch = l & 3;

  for (int rel = 0; rel < RR; ++rel) {
    const float* zsr = zsd + (size_t)rel*n;
    const float* zdr = zsd + (size_t)(6+rel)*n;
    int o0 = off[(size_t)rel*NN + g];
    int deg = off[(size_t)rel*NN + g + 1] - o0;
    float acc[8] = {0,0,0,0,0,0,0,0};
    float esum = 0.f;
    float inv = 0.f;
    if (deg > 0) {
      float zdd = zdr[g];
      for (int base = 0; base < deg; base += 8) {
        int i0 = base + sub, i1 = base + 4 + sub;
        float e0 = 0.f, e1 = 0.f; int s0 = 0, s1 = 0;
        if (i0 < deg) {
          s0 = elist[o0+i0];
          e0 = wexp(zsr[s0] + zdd);
        }
        if (i1 < deg) {
          s1 = elist[o0+i1];
          e1 = wexp(zsr[s1] + zdd);
        }
        esum += e0 + e1;
        uint4 v0 = *(const uint4*)(x0h + (size_t)s0*32 + ch*8);
        uint4 v1 = *(const uint4*)(x0h + (size_t)s1*32 + ch*8);
        acc[0] = fmaf(e0, __uint_as_float(v0.x << 16),         acc[0]);
        acc[1] = fmaf(e0, __uint_as_float(v0.x & 0xffff0000u), acc[1]);
        acc[2] = fmaf(e0, __uint_as_float(v0.y << 16),         acc[2]);
        acc[3] = fmaf(e0, __uint_as_float(v0.y & 0xffff0000u), acc[3]);
        acc[4] = fmaf(e0, __uint_as_float(v0.z << 16),         acc[4]);
        acc[5] = fmaf(e0, __uint_as_float(v0.z & 0xffff0000u), acc[5]);
        acc[6] = fmaf(e0, __uint_as_float(v0.w << 16),         acc[6]);
        acc[7] = fmaf(e0, __uint_as_float(v0.w & 0xffff0000u), acc[7]);
        acc[0] = fmaf(e1, __uint_as_float(v1.x << 16),         acc[0]);
        acc[1] = fmaf(e1, __uint_as_float(v1.x & 0xffff0000u), acc[1]);
        acc[2] = fmaf(e1, __uint_as_float(v1.y << 16),         acc[2]);
        acc[3] = fmaf(e1, __uint_as_float(v1.y & 0xffff0000u), acc[3]);
        acc[4] = fmaf(e1, __uint_as_float(v1.z << 16),         acc[4]);
        acc[5] = fmaf(e1, __uint_as_float(v1.z & 0xffff0000u), acc[5]);
        acc[6] = fmaf(e1, __uint_as_float(v1.w << 16),         acc[6]);
        acc[7] = fmaf(e1, __uint_as_float(v1.w & 0xffff0000u), acc[7]);
      }
      esum += __shfl_xor(esum, 4);
      esum += __shfl_xor(esum, 8);
      #pragma unroll
      for (int j = 0; j < 8; ++j) {
        acc[j] += __shfl_xor(acc[j], 4);
        acc[j] += __shfl_xor(acc[j], 8);
      }
      inv = 1.f / esum;
    }
    if (sub == 0) {
      uint4 ph;
      unsigned* php = (unsigned*)&ph;
      #pragma unroll
      for (int j2 = 0; j2 < 4; ++j2) {
        float a0 = acc[2*j2]   * inv;
        float a1 = acc[2*j2+1] * inv;
        php[j2] = ((unsigned)f2bf(a1) << 16) | f2bf(a0);
      }
      *(uint4*)(aggH + ((size_t)rel*n + g)*32 + ch*8) = ph;
    }
  }
}

// ================= layer-1 concat-GEMM; A bf16-only, W hi/lo (proven r14) ============
__device__ __forceinline__ bf16x8 ldfragG(const short* __restrict__ p, int row, int kb, int KP_)
{
  bf16x4 a = *(const bf16x4*)(p + (size_t)row*KP_ + kb);
  bf16x4 b = *(const bf16x4*)(p + (size_t)row*KP_ + kb + 16);
  return __builtin_shufflevector(a, b, 0,1,2,3,4,5,6,7);
}

__global__ __launch_bounds__(256, 4)
void k_gemm1(const short* __restrict__ aggH,
             const short* __restrict__ Wh, const short* __restrict__ Wl,
             const float* __restrict__ bsv,
             const float* __restrict__ nw, const float* __restrict__ nb,
             unsigned short* __restrict__ Yh, int n)
{
  __shared__ __align__(16) float Cs[32*136];
  int tid = threadIdx.x;
  int r0 = blockIdx.x * 32;
  int wid = tid >> 6, lane = tid & 63;
  int lr = lane & 15, lg = lane >> 4;
  int rt = wid >> 1;
  int c0 = (wid & 1) * 4;
  int arow = r0 + rt*16 + lr;
  int kb = 4*lg;
  f32x4 acct[4] = {{0,0,0,0},{0,0,0,0},{0,0,0,0},{0,0,0,0}};

  for (int rel = 0; rel < RR; ++rel) {
    const short* Ahr = aggH + (size_t)rel*n*32;
    const short* Whr = Wh + (size_t)rel*128*32;
    const short* Wlr = Wl + (size_t)rel*128*32;
    bf16x8 ah = ldfragG(Ahr, arow, kb, 32);
    #pragma unroll
    for (int t = 0; t < 4; ++t) {
      int wrow = (c0 + t)*16 + lr;
      bf16x8 whf = ldfragG(Whr, wrow, kb, 32);
      bf16x8 wlf = ldfragG(Wlr, wrow, kb, 32);
      acct[t] = __builtin_amdgcn_mfma_f32_16x16x32_bf16(ah, whf, acct[t], 0, 0, 0);
      acct[t] = __builtin_amdgcn_mfma_f32_16x16x32_bf16(ah, wlf, acct[t], 0, 0, 0);
    }
  }

  #pragma unroll
  for (int t = 0; t < 4; ++t)
    #pragma unroll
    for (int v = 0; v < 4; ++v) {
      int row = rt*16 + lg*4 + v;
      int col = (c0 + t)*16 + lr;
      float x = acct[t][v] + bsv[col];
      Cs[row*136 + col] = 0.5f*x*(1.f + erff(x*0.70710678118654752f));
    }
  __syncthreads();
  {
    int r = tid >> 3, sg = tid & 7;
    float vals[16];
    float s = 0.f;
    #pragma unroll
    for (int i = 0; i < 16; ++i) { vals[i] = Cs[r*136 + sg*16 + i]; s += vals[i]; }
    s += __shfl_xor(s, 1); s += __shfl_xor(s, 2); s += __shfl_xor(s, 4);
    float mu = s * (1.f/128.f);
    float var = 0.f;
    #pragma unroll
    for (int i = 0; i < 16; ++i) { vals[i] -= mu; var += vals[i]*vals[i]; }
    var += __shfl_xor(var, 1); var += __shfl_xor(var, 2); var += __shfl_xor(var, 4);
    float inv = 1.f / sqrtf(var*(1.f/128.f) + 1e-5f);
    int g = r0 + r;
    uint4 ph0, ph1;
    unsigned* php0 = (unsigned*)&ph0; unsigned* php1 = (unsigned*)&ph1;
    #pragma unroll
    for (int j2 = 0; j2 < 8; ++j2) {
      int c = sg*16 + 2*j2;
      float y0 = vals[2*j2]  *inv*nw[c]   + nb[c];
      float y1 = vals[2*j2+1]*inv*nw[c+1] + nb[c+1];
      unsigned hw = ((unsigned)f2bf(y1) << 16) | f2bf(y0);
      if (j2 < 4) php0[j2] = hw; else php1[j2-4] = hw;
    }
    *(uint4*)(Yh + (size_t)g*128 + sg*16)     = ph0;
    *(uint4*)(Yh + (size_t)g*128 + sg*16 + 8) = ph1;
  }
}

// ================= layer-2 aggregation: ONE-PASS, all 6 relations (proven r16) ======
#define ACC8(W_, U_) \
  tmp[0] = fmaf(W_, __uint_as_float((U_).x << 16),         tmp[0]); \
  tmp[1] = fmaf(W_, __uint_as_float((U_).x & 0xffff0000u), tmp[1]); \
  tmp[2] = fmaf(W_, __uint_as_float((U_).y << 16),         tmp[2]); \
  tmp[3] = fmaf(W_, __uint_as_float((U_).y & 0xffff0000u), tmp[3]); \
  tmp[4] = fmaf(W_, __uint_as_float((U_).z << 16),         tmp[4]); \
  tmp[5] = fmaf(W_, __uint_as_float((U_).z & 0xffff0000u), tmp[5]); \
  tmp[6] = fmaf(W_, __uint_as_float((U_).w << 16),         tmp[6]); \
  tmp[7] = fmaf(W_, __uint_as_float((U_).w & 0xffff0000u), tmp[7]);

__global__ void k_agg2(const unsigned short* __restrict__ h1,
                       const float* __restrict__ zsd,
                       const int* __restrict__ elist,
                       const int* __restrict__ off,
                       unsigned short* __restrict__ A0,   // [3][n][128] rels 0-2
                       unsigned short* __restrict__ A1,   // [2][n][128] rels 3-4
                       unsigned short* __restrict__ A2,   // [n][128] rel 5
                       int n)
{
  int gid = blockIdx.x*256 + threadIdx.x;
  int g = gid >> 4;
  int l = threadIdx.x & 15;
  int gbase = threadIdx.x & 48;
  if (g >= n) return;

  for (int r = 0; r < RR; ++r) {
    int o0 = off[(size_t)r*NN + g], o1 = off[(size_t)r*NN + g + 1];
    int deg = o1 - o0;
    float tmp[8] = {0,0,0,0,0,0,0,0};
    float inv = 0.f;
    if (deg > 0) {
      const float* zsr = zsd + (size_t)r*n;
      float zdd = zsd[(size_t)(6+r)*n + g];
      float esum = 0.f;
      for (int base = 0; base < deg; base += 16) {
        int i = base + l;
        float ew = 0.f; int s = 0;
        if (i < deg) {
          s = elist[o0+i];
          ew = wexp(zsr[s] + zdd);
        }
        esum += ew;
        int cnt = min(16, deg - base);
        for (int t = 0; t < cnt; t += 4) {
          float w0 = __shfl(ew, gbase + t);
          float w1 = __shfl(ew, gbase + t + 1);
          float w2 = __shfl(ew, gbase + t + 2);
          float w3 = __shfl(ew, gbase + t + 3);
          int a0 = __shfl(s, gbase + t);
          int a1 = __shfl(s, gbase + t + 1);
          int a2 = __shfl(s, gbase + t + 2);
          int a3 = __shfl(s, gbase + t + 3);
          uint4 u0 = *(const uint4*)(h1 + (size_t)a0*128 + l*8);
          uint4 u1 = *(const uint4*)(h1 + (size_t)a1*128 + l*8);
          uint4 u2 = *(const uint4*)(h1 + (size_t)a2*128 + l*8);
          uint4 u3 = *(const uint4*)(h1 + (size_t)a3*128 + l*8);
          ACC8(w0, u0);
          ACC8(w1, u1);
          ACC8(w2, u2);
          ACC8(w3, u3);
        }
      }
      esum += __shfl_xor(esum, 1);
      esum += __shfl_xor(esum, 2);
      esum += __shfl_xor(esum, 4);
      esum += __shfl_xor(esum, 8);
      inv = 1.f / esum;
    }
    unsigned short* outp = (r < 3) ? A0 + (size_t)r*n*128
                         : (r < 5) ? A1 + (size_t)(r-3)*n*128
                                   : A2;
    uint4 ph;
    unsigned* php = (unsigned*)&ph;
    #pragma unroll
    for (int j2 = 0; j2 < 4; ++j2) {
      float a0 = tmp[2*j2]   * inv;
      float a1 = tmp[2*j2+1] * inv;
      php[j2] = ((unsigned)f2bf(a1) << 16) | f2bf(a0);
    }
    *(uint4*)(outp + (size_t)g*128 + l*8) = ph;
  }
}

// ================= layer-2 concat-GEMM v6: all A loads hoisted to entry ==========
__global__ __launch_bounds__(256, 3)
void k_gemm2(const unsigned short* __restrict__ A0,   // rels 0-2
             const unsigned short* __restrict__ A1,   // rels 3-4
             const unsigned short* __restrict__ A2,   // rel 5
             const short* __restrict__ WhAll, const short* __restrict__ WlAll,
             const float* __restrict__ bsv,
             const float* __restrict__ nw, const float* __restrict__ nb,
             unsigned short* __restrict__ Yb,         // h2 bf16 out
             const float* __restrict__ q, const int* __restrict__ batch,
             float* __restrict__ scores, unsigned* __restrict__ bmax, int n)
{
  constexpr int KP = 128;
  __shared__ __align__(16) short lds[128*KP];   // one W plane (fragment layout) = 32 KB
  int tid = threadIdx.x;
  int r0 = blockIdx.x * 64;
  int wid = tid >> 6, lane = tid & 63;
  int lr = lane & 15, lg = lane >> 4;
  int grow = r0 + wid*16 + lr;
  int growc = min(grow, n-1);
  f32x4 acc[8] = {{0,0,0,0},{0,0,0,0},{0,0,0,0},{0,0,0,0},
                  {0,0,0,0},{0,0,0,0},{0,0,0,0},{0,0,0,0}};

  // hoist ALL A-fragment loads (6 rels x 4 kc) -- latency hides under W pipeline
  bf16x8 af[RR][4];
  #pragma unroll
  for (int rel = 0; rel < RR; ++rel) {
    const unsigned short* Ar = (rel < 3) ? A0 + (size_t)rel*n*KP
                             : (rel < 5) ? A1 + (size_t)(rel-3)*n*KP
                                         : A2;
    #pragma unroll
    for (int kc = 0; kc < 4; ++kc)
      af[rel][kc] = ldfragG((const short*)Ar, growc, kc*32 + 4*lg, KP);
  }

  #pragma unroll
  for (int rel = 0; rel < RR; ++rel) {
    const short* Wh = WhAll + (size_t)rel*128*KP;
    const short* Wl = WlAll + (size_t)rel*128*KP;
    // phase H
    for (int ch = tid; ch < 128*16; ch += 256)
      *(bf16x8*)(lds + (size_t)ch*8) = *(const bf16x8*)(Wh + (size_t)ch*8);
    __syncthreads();
    #pragma unroll
    for (int kc = 0; kc < 4; ++kc) {
      int fbase = ((kc*4 + lg)*128)*8;
      #pragma unroll
      for (int ct = 0; ct < 8; ++ct) {
        bf16x8 wf = *(const bf16x8*)(lds + fbase + (ct*16 + lr)*8);
        acc[ct] = __builtin_amdgcn_mfma_f32_16x16x32_bf16(af[rel][kc], wf, acc[ct], 0, 0, 0);
      }
    }
    __syncthreads();
    // phase L
    for (int ch = tid; ch < 128*16; ch += 256)
      *(bf16x8*)(lds + (size_t)ch*8) = *(const bf16x8*)(Wl + (size_t)ch*8);
    __syncthreads();
    #pragma unroll
    for (int kc = 0; kc < 4; ++kc) {
      int fbase = ((kc*4 + lg)*128)*8;
      #pragma unroll
      for (int ct = 0; ct < 8; ++ct) {
        bf16x8 wf = *(const bf16x8*)(lds + fbase + (ct*16 + lr)*8);
        acc[ct] = __builtin_amdgcn_mfma_f32_16x16x32_bf16(af[rel][kc], wf, acc[ct], 0, 0, 0);
      }
    }
    __syncthreads();
  }

  // epilogue: bias + gelu + LN + bf16 h2 + fused pool score (per-wave, no LDS)
  #pragma unroll
  for (int v = 0; v < 4; ++v) {
    int row = r0 + wid*16 + lg*4 + v;
    float vals[8];
    float s = 0.f;
    #pragma unroll
    for (int ct = 0; ct < 8; ++ct) {
      int c = ct*16 + lr;
      float x = acc[ct][v] + bsv[c];
      x = 0.5f*x*(1.f + erff(x*0.70710678118654752f));
      vals[ct] = x;
      s += x;
    }
    s += __shfl_xor(s, 1); s += __shfl_xor(s, 2);
    s += __shfl_xor(s, 4); s += __shfl_xor(s, 8);
    float mu = s * (1.f/128.f);
    float var = 0.f;
    #pragma unroll
    for (int ct = 0; ct < 8; ++ct) { vals[ct] -= mu; var += vals[ct]*vals[ct]; }
    var += __shfl_xor(var, 1); var += __shfl_xor(var, 2);
    var += __shfl_xor(var, 4); var += __shfl_xor(var, 8);
    float inv = 1.f / sqrtf(var*(1.f/128.f) + 1e-5f);
    float sc = 0.f;
    #pragma unroll
    for (int ct = 0; ct < 8; ++ct) {
      int c = ct*16 + lr;
      float y = vals[ct]*inv*nw[c] + nb[c];
      if (row < n) Yb[(size_t)row*128 + c] = f2bf(y);
      sc = fmaf(y, q[c], sc);
    }
    sc += __shfl_xor(sc, 1); sc += __shfl_xor(sc, 2);
    sc += __shfl_xor(sc, 4); sc += __shfl_xor(sc, 8);
    if (lr == 0 && row < n) {
      scores[row] = sc;
      atomicMax(&bmax[batch[row]], fenc(sc));
    }
  }
}

// ================= bias-sum =================
__global__ void k_bsum(const float* __restrict__ b, float* __restrict__ bs)
{
  int t = threadIdx.x;
  float s = 0.f;
  #pragma unroll
  for (int r = 0; r < RR; ++r) s += b[r*HH + t];
  bs[t] = s;
}

// ================= pooling =================
__global__ void k_segbounds(const int* __restrict__ batch, int* __restrict__ segst,
                            int n, int numB)
{
  int b = blockIdx.x*256 + threadIdx.x;
  if (b > numB) return;
  int lo = 0, hi = n;
  while (lo < hi) { int mid = (lo+hi) >> 1; if (batch[mid] < b) lo = mid+1; else hi = mid; }
  segst[b] = lo;
}

__global__ void k_pool(const unsigned short* __restrict__ X, const float* __restrict__ scores,
                       const int* __restrict__ segst, const unsigned* __restrict__ bmax,
                       float* __restrict__ pool, int numB)
{
  int b = blockIdx.x;
  int t = threadIdx.x;
  int s0 = segst[b], s1 = segst[b+1];
  float m = fdec(bmax[b]);
  float acc0 = 0.f, acc1 = 0.f, esum = 0.f;
  int i = s0;
  for (; i + 1 < s1; i += 2) {
    float e0 = __expf(scores[i] - m);
    float e1 = __expf(scores[i+1] - m);
    esum += e0 + e1;
    acc0 = fmaf(e0, bf2f(X[(size_t)i*128 + t]), acc0);
    acc1 = fmaf(e1, bf2f(X[(size_t)(i+1)*128 + t]), acc1);
  }
  if (i < s1) {
    float e0 = __expf(scores[i] - m);
    esum += e0;
    acc0 = fmaf(e0, bf2f(X[(size_t)i*128 + t]), acc0);
  }
  float inv = (s1 > s0) ? 1.f/esum : 0.f;
  pool[(size_t)b*128 + t] = (acc0 + acc1) * inv;
}

__global__ void k_outgemm(const float* __restrict__ pool, const float* __restrict__ projW,
                          const float* __restrict__ projb, float* __restrict__ out, int numB)
{
  int b = blockIdx.x;
  int j = threadIdx.x;
  __shared__ float p[128];
  p[j] = pool[(size_t)b*128 + j];
  __syncthreads();
  float acc = projb[j];
  #pragma unroll 16
  for (int k = 0; k < 128; ++k) acc = fmaf(p[k], projW[(size_t)k*128 + j], acc);
  out[(size_t)b*128 + j] = acc;
}

// ================= launcher =================
extern "C" void kernel_launch(void* const* d_in, const int* in_sizes, int n_in,
                              void* d_out, int out_size, void* d_ws, size_t ws_size,
                              hipStream_t stream)
{
  const float* x_all = (const float*)d_in[0];
  const int*   edges = (const int*)d_in[1];
  const int*   batch = (const int*)d_in[2];
  const float* pos_table = (const float*)d_in[3];
  const float* W1  = (const float*)d_in[4];
  const float* as1 = (const float*)d_in[5];
  const float* ad1 = (const float*)d_in[6];
  const float* b1  = (const float*)d_in[7];
  const float* W2  = (const float*)d_in[8];
  const float* as2 = (const float*)d_in[9];
  const float* ad2 = (const float*)d_in[10];
  const float* b2  = (const float*)d_in[11];
  const float* n1w = (const float*)d_in[12];
  const float* n1b = (const float*)d_in[13];
  const float* n2w = (const float*)d_in[14];
  const float* n2b = (const float*)d_in[15];
  const float* query = (const float*)d_in[16];
  const float* projW = (const float*)d_in[17];
  const float* projb = (const float*)d_in[18];
  float* out = (float*)d_out;
  (void)in_sizes; (void)n_in; (void)out_size; (void)ws_size;

  char* p = (char*)d_ws;
  auto alloc = [&](size_t b){ void* r = (void*)p; p += (b + 255) & ~(size_t)255; return r; };
  int*   off   = (int*)alloc((size_t)(MM+1)*sizeof(int));
  int*   elist = (int*)alloc((size_t)RR*EE*sizeof(int));
  int*   boff  = (int*)alloc((size_t)(NBK+1)*sizeof(int));
  int*   bcur  = (int*)alloc((size_t)NBK*sizeof(int));
  short* wtH   = (short*)alloc((size_t)RR*128*128*sizeof(short));
  short* wtL   = (short*)alloc((size_t)RR*128*128*sizeof(short));
  float* wa    = (float*)alloc((size_t)12*128*sizeof(float));
  float* zsd   = (float*)alloc((size_t)12*NN*sizeof(float));
  float* bsv   = (float*)alloc(128*sizeof(float));
  int*   segst = (int*)alloc((size_t)(BB+1)*sizeof(int));
  unsigned* bmax = (unsigned*)alloc((size_t)BB*sizeof(unsigned));
  float* pool  = (float*)alloc((size_t)BB*HH*sizeof(float));
  float* scrs  = (float*)alloc((size_t)NN*sizeof(float));
  unsigned short* big = (unsigned short*)alloc((size_t)3*NN*128*sizeof(short)); // aggH; agg2 rels 0-2
  float* R1    = (float*)alloc((size_t)NN*128*sizeof(float));  // ebkt -> x0 -> agg2 rels 3-4
  float* R2    = (float*)alloc((size_t)NN*128*sizeof(float));  // h1h | agg2 rel 5; h2 bf16

  unsigned* ebkt = (unsigned*)R1;               // 38.4MB, dead after bbuild
  short* x0h = (short*)R1;                      // 12.8MB, dead after agg1
  short* x0l = x0h + (size_t)NN*32;
  unsigned short* agg2b = (unsigned short*)R1;  // [2][N][128] (rels 3-4)
  unsigned short* h1h = (unsigned short*)R2;    // [N][128] front 25.6MB
  unsigned short* agg2c = h1h + (size_t)NN*128; // [N][128] back 25.6MB (rel 5)
  unsigned short* h2b = h1h;                    // bf16 h2 overwrites dead h1h
  unsigned short* aggH = big;                   // [6][N][32]
  unsigned short* agg2a = big;                  // [3][N][128] (rels 0-2, after gemm1)

  // --- CSR build ---
  const int nch = (EE + CH - 1) / CH;
  hipMemsetAsync(bcur, 0, (size_t)NBK*sizeof(int), stream);
  k_binscatter<<<RR*nch,256,0,stream>>>(edges, bcur, ebkt);
  k_bscan<<<1,256,0,stream>>>(bcur, boff, off);
  k_bbuild<<<NBK,256,0,stream>>>(ebkt, bcur, boff, off, elist);

  // --- prep ---
  k_featprep<<<ceil_div(NN*32,256),256,0,stream>>>(x_all, pos_table, x0h, x0l);
  k_segbounds<<<ceil_div(BB+1,256),256,0,stream>>>(batch, segst, NN, BB);
  hipMemsetAsync(bmax, 0, (size_t)BB*sizeof(unsigned), stream);

  // --- layer 1 ---
  k_wa<32><<<ceil_div(12*32,256),256,0,stream>>>(W1, as1, ad1, 21, wa);
  k_zsd32<<<ceil_div(NN,256),256,0,stream>>>(x0h, x0l, wa, zsd, NN);
  k_wprep<32><<<ceil_div(RR*128*32,256),256,0,stream>>>(W1, 21, wtH, wtL);
  k_bsum<<<1,128,0,stream>>>(b1, bsv);
  k_agg1<<<ceil_div(NN*16,256),256,0,stream>>>((const unsigned short*)x0h, zsd, elist, off,
                                               aggH, NN);
  k_gemm1<<<ceil_div(NN,32),256,0,stream>>>((const short*)aggH,
                                            wtH, wtL, bsv, n1w, n1b, h1h, NN);

  // --- layer 2: single 6-rel aggregate, then single 6-rel GEMM ---
  k_wa<128><<<ceil_div(12*128,256),256,0,stream>>>(W2, as2, ad2, 128, wa);
  k_zsd128<<<ceil_div(NN*16,256),256,0,stream>>>(h1h, wa, zsd, NN);
  k_wprep2<<<ceil_div(RR*128*128,256),256,0,stream>>>(W2, wtH, wtL);
  k_bsum<<<1,128,0,stream>>>(b2, bsv);
  k_agg2<<<ceil_div(NN*16,256),256,0,stream>>>(h1h, zsd, elist, off,
      agg2a, agg2b, agg2c, NN);
  k_gemm2<<<ceil_div(NN,64),256,0,stream>>>(agg2a, agg2b, agg2c, wtH, wtL,
      bsv, n2w, n2b, h2b, query, batch, scrs, bmax, NN);

  // --- attention pooling ---
  k_pool<<<BB,128,0,stream>>>(h2b, scrs, segst, bmax, pool, BB);
  k_outgemm<<<BB,128,0,stream>>>(pool, projW, projb, out, BB);
}

// Round 18
// 735.365 us; speedup vs baseline: 1.0822x; 1.0822x over previous
//
#include <hip/hip_runtime.h>
#include <math.h>

#define NN   100000
#define EE   800000
#define RR   6
#define BB   1000
#define HH   128
#define MM   (RR*NN)
#define NBPR ((NN + 255) >> 8)
#define NBK  (RR * NBPR)
#define CH   4096
#define CAP  4096     // fixed capacity per bucket in ebkt staging

static inline int ceil_div(int a, int b){ return (a+b-1)/b; }

typedef __attribute__((ext_vector_type(8))) short bf16x8;
typedef __attribute__((ext_vector_type(4))) short bf16x4;
typedef __attribute__((ext_vector_type(4))) float f32x4;

__device__ __forceinline__ unsigned fenc(float f){
  unsigned u = __float_as_uint(f);
  return (u & 0x80000000u) ? ~u : (u | 0x80000000u);
}
__device__ __forceinline__ float fdec(unsigned u){
  return __uint_as_float((u & 0x80000000u) ? (u & 0x7fffffffu) : ~u);
}
__device__ __forceinline__ unsigned short f2bf(float f){
  unsigned u = __float_as_uint(f);
  return (unsigned short)((u + 0x7fffu + ((u >> 16) & 1u)) >> 16);
}
__device__ __forceinline__ float bf2f(unsigned short h){
  return __uint_as_float(((unsigned)h) << 16);
}
__device__ __forceinline__ float wexp(float z){
  z = (z > 0.f) ? z : 0.2f*z;              // LeakyReLU(0.2)
  z = fminf(fmaxf(z, -60.f), 60.f);        // keep exp finite (|z|<=10 in practice)
  return __expf(z);
}

// ================= CSR build: fixed-capacity binning (proven r9) =================
__global__ void k_binscatter(const int* __restrict__ edges, int* __restrict__ bcur,
                             unsigned* __restrict__ ebkt)
{
  __shared__ int hist[NBPR];
  __shared__ int base[NBPR];
  int t = threadIdx.x;
  const int nch = (EE + CH - 1) / CH;
  int r = blockIdx.x / nch, c = blockIdx.x - r*nch;
  for (int i = t; i < NBPR; i += 256) hist[i] = 0;
  __syncthreads();
  const int* sptr = edges + (size_t)r*2*EE;
  const int* dptr = sptr + EE;
  int e0 = c*CH, e1 = min(EE, e0 + CH);
  for (int i = e0 + t; i < e1; i += 256)
    atomicAdd(&hist[dptr[i] >> 8], 1);
  __syncthreads();
  for (int i = t; i < NBPR; i += 256) {
    int h = hist[i];
    int gb = r*NBPR + i;
    base[i] = h ? (gb*CAP + atomicAdd(&bcur[gb], h)) : 0;
    hist[i] = 0;
  }
  __syncthreads();
  for (int i = e0 + t; i < e1; i += 256) {
    int dst = dptr[i];
    int b = dst >> 8;
    int slot = base[b] + atomicAdd(&hist[b], 1);
    ebkt[slot] = ((unsigned)sptr[i] << 8) | (unsigned)(dst & 255);
  }
}

__global__ void k_bscan(const int* __restrict__ bcur, int* __restrict__ boff,
                        int* __restrict__ off)
{
  __shared__ int sh[256];
  int t = threadIdx.x;
  int carry = 0;
  for (int c = 0; c < NBK; c += 256) {
    int idx = c + t;
    int v = (idx < NBK) ? bcur[idx] : 0;
    sh[t] = v;
    __syncthreads();
    for (int o = 1; o < 256; o <<= 1) {
      int add = (t >= o) ? sh[t-o] : 0;
      __syncthreads();
      sh[t] += add;
      __syncthreads();
    }
    int incl = sh[t];
    int tot  = sh[255];
    if (idx < NBK) boff[idx] = carry + incl - v;
    __syncthreads();
    carry += tot;
  }
  if (t == 0) { boff[NBK] = carry; off[MM] = carry; }
}

__global__ void k_bbuild(const unsigned* __restrict__ ebkt, const int* __restrict__ bcur,
                         const int* __restrict__ boff,
                         int* __restrict__ off, int* __restrict__ elist)
{
  __shared__ int cnt[256];
  __shared__ int sc[256];
  __shared__ int cur[256];
  int t = threadIdx.x;
  int bb = blockIdx.x;
  int e0r = bb*CAP, e1r = e0r + bcur[bb];
  int w0 = boff[bb];
  cnt[t] = 0;
  __syncthreads();
  for (int i = e0r + t; i < e1r; i += 256)
    atomicAdd(&cnt[ebkt[i] & 255u], 1);
  __syncthreads();
  sc[t] = cnt[t];
  __syncthreads();
  for (int o = 1; o < 256; o <<= 1) {
    int add = (t >= o) ? sc[t-o] : 0;
    __syncthreads();
    sc[t] += add;
    __syncthreads();
  }
  int excl = sc[t] - cnt[t];
  int r = bb / NBPR, b = bb - r*NBPR;
  int dst = b*256 + t;
  if (dst < NN) off[r*NN + dst] = w0 + excl;
  cur[t] = w0 + excl;
  __syncthreads();
  for (int i = e0r + t; i < e1r; i += 256) {
    unsigned w = ebkt[i];
    int slot = atomicAdd(&cur[w & 255u], 1);
    elist[slot] = (int)(w >> 8);
  }
}

// ================= feature prep (bf16 hi/lo planes, K padded 21->32) =================
__global__ void k_featprep(const float* __restrict__ x_all, const float* __restrict__ pos_table,
                           short* __restrict__ x0h, short* __restrict__ x0l)
{
  int gid = blockIdx.x*256 + threadIdx.x;
  if (gid >= NN*32) return;
  int nidx = gid >> 5, c = gid & 31;
  float v = 0.f;
  if (c < 13) {
    int scl = (c < 5) ? c : c + 1;
    v = x_all[nidx*14 + scl];
  } else if (c < 21) {
    int pi = (int)x_all[nidx*14 + 5];
    pi = pi < 0 ? 0 : (pi > 23 ? 23 : pi);
    v = pos_table[pi*8 + (c - 13)];
  }
  unsigned short h = f2bf(v);
  unsigned short l = f2bf(v - bf2f(h));
  x0h[gid] = (short)h;
  x0l[gid] = (short)l;
}

// ================= weight prep (layer-1, row-major [r][out][KP]) =================
template<int KP>
__global__ void k_wprep(const float* __restrict__ W, int K,
                        short* __restrict__ Wh, short* __restrict__ Wl)
{
  int gid = blockIdx.x*256 + threadIdx.x;
  if (gid >= RR*128*KP) return;
  int r = gid / (128*KP);
  int rem = gid - r*(128*KP);
  int nn = rem / KP, k = rem - nn*KP;
  float v = (k < K) ? W[((size_t)r*K + k)*128 + nn] : 0.f;
  unsigned short h = f2bf(v);
  unsigned short l = f2bf(v - bf2f(h));
  Wh[gid] = (short)h;
  Wl[gid] = (short)l;
}

// ================= weight prep (layer-2, MFMA fragment layout) =================
__global__ void k_wprep2(const float* __restrict__ W,
                         short* __restrict__ Wh, short* __restrict__ Wl)
{
  int gid = blockIdx.x*256 + threadIdx.x;
  if (gid >= RR*128*128) return;
  int r = gid / (128*128);
  int i = gid - r*(128*128);
  int kc = i >> 12;
  int lg = (i >> 10) & 3;
  int row = (i >> 3) & 127;
  int e = i & 7;
  int k = kc*32 + 16*(e >> 2) + 4*lg + (e & 3);
  float v = W[((size_t)r*128 + k)*128 + row];
  unsigned short h = f2bf(v);
  unsigned short l = f2bf(v - bf2f(h));
  Wh[gid] = (short)h;
  Wl[gid] = (short)l;
}

// ================= wa: precompute W_r @ a =================
template<int KP>
__global__ void k_wa(const float* __restrict__ W, const float* __restrict__ as,
                     const float* __restrict__ ad, int K, float* __restrict__ wa)
{
  int idx = blockIdx.x*256 + threadIdx.x;
  if (idx >= 12*KP) return;
  int rr = idx / KP, k = idx - rr*KP;
  int r = (rr < 6) ? rr : rr - 6;
  const float* a = ((rr < 6) ? as : ad) + (size_t)r*HH;
  float s = 0.f;
  if (k < K) {
    const float* wrow = W + ((size_t)r*K + k)*128;
    #pragma unroll 8
    for (int h = 0; h < 128; ++h) s = fmaf(wrow[h], a[h], s);
  }
  wa[idx] = s;
}

// ================= zsd layer-1: [12][N] from x0 hi/lo =================
__global__ void k_zsd32(const short* __restrict__ xh, const short* __restrict__ xl,
                        const float* __restrict__ wa, float* __restrict__ zsd, int n)
{
  __shared__ float w[12*32];
  int tid = threadIdx.x;
  for (int i = tid; i < 12*32; i += 256) w[i] = wa[i];
  __syncthreads();
  int g = blockIdx.x*256 + tid;
  if (g >= n) return;
  float v[32];
  #pragma unroll
  for (int c = 0; c < 4; ++c) {
    uint4 vh = *(const uint4*)(xh + (size_t)g*32 + c*8);
    uint4 vl = *(const uint4*)(xl + (size_t)g*32 + c*8);
    const unsigned short* hp = (const unsigned short*)&vh;
    const unsigned short* lp = (const unsigned short*)&vl;
    #pragma unroll
    for (int j = 0; j < 8; ++j) v[c*8+j] = bf2f(hp[j]) + bf2f(lp[j]);
  }
  #pragma unroll
  for (int rr = 0; rr < 12; ++rr) {
    float d = 0.f;
    #pragma unroll
    for (int k = 0; k < 32; ++k) d = fmaf(v[k], w[rr*32+k], d);
    zsd[(size_t)rr*n + g] = d;
  }
}

// ================= zsd layer-2: [12][N] from h1 bf16-only =================
__global__ void k_zsd128(const unsigned short* __restrict__ xh,
                         const float* __restrict__ wa, float* __restrict__ zsd, int n)
{
  __shared__ float w[12*128];
  int tid = threadIdx.x;
  for (int i = tid; i < 12*128; i += 256) w[i] = wa[i];
  __syncthreads();
  int gid = blockIdx.x*256 + tid;
  int g = gid >> 4, l = tid & 15;
  if (g >= n) return;
  uint4 vh = *(const uint4*)(xh + (size_t)g*128 + l*8);
  const unsigned short* hp = (const unsigned short*)&vh;
  float v[8];
  #pragma unroll
  for (int j = 0; j < 8; ++j) v[j] = bf2f(hp[j]);
  float dot[12];
  #pragma unroll
  for (int rr = 0; rr < 12; ++rr) {
    float p = 0.f;
    #pragma unroll
    for (int j = 0; j < 8; ++j) p = fmaf(v[j], w[rr*128 + l*8 + j], p);
    p += __shfl_xor(p, 1); p += __shfl_xor(p, 2);
    p += __shfl_xor(p, 4); p += __shfl_xor(p, 8);
    dot[rr] = p;
  }
  if (l < 12) zsd[(size_t)l*n + g] = dot[l];
}

// ================= layer-1 aggregation: ONE-PASS, bf16-only output =================
__global__ void k_agg1(const unsigned short* __restrict__ x0h, const float* __restrict__ zsd,
                       const int* __restrict__ elist, const int* __restrict__ off,
                       unsigned short* __restrict__ aggH, int n)
{
  int gid = blockIdx.x*256 + threadIdx.x;
  int g = gid >> 4;
  int l = threadIdx.x & 15;
  if (g >= n) return;
  int sub = l >> 2, ch = l & 3;

  for (int rel = 0; rel < RR; ++rel) {
    const float* zsr = zsd + (size_t)rel*n;
    const float* zdr = zsd + (size_t)(6+rel)*n;
    int o0 = off[(size_t)rel*NN + g];
    int deg = off[(size_t)rel*NN + g + 1] - o0;
    float acc[8] = {0,0,0,0,0,0,0,0};
    float esum = 0.f;
    float inv = 0.f;
    if (deg > 0) {
      float zdd = zdr[g];
      for (int base = 0; base < deg; base += 8) {
        int i0 = base + sub, i1 = base + 4 + sub;
        float e0 = 0.f, e1 = 0.f; int s0 = 0, s1 = 0;
        if (i0 < deg) {
          s0 = elist[o0+i0];
          e0 = wexp(zsr[s0] + zdd);
        }
        if (i1 < deg) {
          s1 = elist[o0+i1];
          e1 = wexp(zsr[s1] + zdd);
        }
        esum += e0 + e1;
        uint4 v0 = *(const uint4*)(x0h + (size_t)s0*32 + ch*8);
        uint4 v1 = *(const uint4*)(x0h + (size_t)s1*32 + ch*8);
        acc[0] = fmaf(e0, __uint_as_float(v0.x << 16),         acc[0]);
        acc[1] = fmaf(e0, __uint_as_float(v0.x & 0xffff0000u), acc[1]);
        acc[2] = fmaf(e0, __uint_as_float(v0.y << 16),         acc[2]);
        acc[3] = fmaf(e0, __uint_as_float(v0.y & 0xffff0000u), acc[3]);
        acc[4] = fmaf(e0, __uint_as_float(v0.z << 16),         acc[4]);
        acc[5] = fmaf(e0, __uint_as_float(v0.z & 0xffff0000u), acc[5]);
        acc[6] = fmaf(e0, __uint_as_float(v0.w << 16),         acc[6]);
        acc[7] = fmaf(e0, __uint_as_float(v0.w & 0xffff0000u), acc[7]);
        acc[0] = fmaf(e1, __uint_as_float(v1.x << 16),         acc[0]);
        acc[1] = fmaf(e1, __uint_as_float(v1.x & 0xffff0000u), acc[1]);
        acc[2] = fmaf(e1, __uint_as_float(v1.y << 16),         acc[2]);
        acc[3] = fmaf(e1, __uint_as_float(v1.y & 0xffff0000u), acc[3]);
        acc[4] = fmaf(e1, __uint_as_float(v1.z << 16),         acc[4]);
        acc[5] = fmaf(e1, __uint_as_float(v1.z & 0xffff0000u), acc[5]);
        acc[6] = fmaf(e1, __uint_as_float(v1.w << 16),         acc[6]);
        acc[7] = fmaf(e1, __uint_as_float(v1.w & 0xffff0000u), acc[7]);
      }
      esum += __shfl_xor(esum, 4);
      esum += __shfl_xor(esum, 8);
      #pragma unroll
      for (int j = 0; j < 8; ++j) {
        acc[j] += __shfl_xor(acc[j], 4);
        acc[j] += __shfl_xor(acc[j], 8);
      }
      inv = 1.f / esum;
    }
    if (sub == 0) {
      uint4 ph;
      unsigned* php = (unsigned*)&ph;
      #pragma unroll
      for (int j2 = 0; j2 < 4; ++j2) {
        float a0 = acc[2*j2]   * inv;
        float a1 = acc[2*j2+1] * inv;
        php[j2] = ((unsigned)f2bf(a1) << 16) | f2bf(a0);
      }
      *(uint4*)(aggH + ((size_t)rel*n + g)*32 + ch*8) = ph;
    }
  }
}

// ================= layer-1 concat-GEMM; A bf16-only, W hi/lo =================
__device__ __forceinline__ bf16x8 ldfragG(const short* __restrict__ p, int row, int kb, int KP_)
{
  bf16x4 a = *(const bf16x4*)(p + (size_t)row*KP_ + kb);
  bf16x4 b = *(const bf16x4*)(p + (size_t)row*KP_ + kb + 16);
  return __builtin_shufflevector(a, b, 0,1,2,3,4,5,6,7);
}

__global__ __launch_bounds__(256, 4)
void k_gemm1(const short* __restrict__ aggH,
             const short* __restrict__ Wh, const short* __restrict__ Wl,
             const float* __restrict__ bsv,
             const float* __restrict__ nw, const float* __restrict__ nb,
             unsigned short* __restrict__ Yh, int n)
{
  __shared__ __align__(16) float Cs[32*136];
  int tid = threadIdx.x;
  int r0 = blockIdx.x * 32;
  int wid = tid >> 6, lane = tid & 63;
  int lr = lane & 15, lg = lane >> 4;
  int rt = wid >> 1;
  int c0 = (wid & 1) * 4;
  int arow = r0 + rt*16 + lr;
  int kb = 4*lg;
  f32x4 acct[4] = {{0,0,0,0},{0,0,0,0},{0,0,0,0},{0,0,0,0}};

  for (int rel = 0; rel < RR; ++rel) {
    const short* Ahr = aggH + (size_t)rel*n*32;
    const short* Whr = Wh + (size_t)rel*128*32;
    const short* Wlr = Wl + (size_t)rel*128*32;
    bf16x8 ah = ldfragG(Ahr, arow, kb, 32);
    #pragma unroll
    for (int t = 0; t < 4; ++t) {
      int wrow = (c0 + t)*16 + lr;
      bf16x8 whf = ldfragG(Whr, wrow, kb, 32);
      bf16x8 wlf = ldfragG(Wlr, wrow, kb, 32);
      acct[t] = __builtin_amdgcn_mfma_f32_16x16x32_bf16(ah, whf, acct[t], 0, 0, 0);
      acct[t] = __builtin_amdgcn_mfma_f32_16x16x32_bf16(ah, wlf, acct[t], 0, 0, 0);
    }
  }

  #pragma unroll
  for (int t = 0; t < 4; ++t)
    #pragma unroll
    for (int v = 0; v < 4; ++v) {
      int row = rt*16 + lg*4 + v;
      int col = (c0 + t)*16 + lr;
      float x = acct[t][v] + bsv[col];
      Cs[row*136 + col] = 0.5f*x*(1.f + erff(x*0.70710678118654752f));
    }
  __syncthreads();
  {
    int r = tid >> 3, sg = tid & 7;
    float vals[16];
    float s = 0.f;
    #pragma unroll
    for (int i = 0; i < 16; ++i) { vals[i] = Cs[r*136 + sg*16 + i]; s += vals[i]; }
    s += __shfl_xor(s, 1); s += __shfl_xor(s, 2); s += __shfl_xor(s, 4);
    float mu = s * (1.f/128.f);
    float var = 0.f;
    #pragma unroll
    for (int i = 0; i < 16; ++i) { vals[i] -= mu; var += vals[i]*vals[i]; }
    var += __shfl_xor(var, 1); var += __shfl_xor(var, 2); var += __shfl_xor(var, 4);
    float inv = 1.f / sqrtf(var*(1.f/128.f) + 1e-5f);
    int g = r0 + r;
    uint4 ph0, ph1;
    unsigned* php0 = (unsigned*)&ph0; unsigned* php1 = (unsigned*)&ph1;
    #pragma unroll
    for (int j2 = 0; j2 < 8; ++j2) {
      int c = sg*16 + 2*j2;
      float y0 = vals[2*j2]  *inv*nw[c]   + nb[c];
      float y1 = vals[2*j2+1]*inv*nw[c+1] + nb[c+1];
      unsigned hw = ((unsigned)f2bf(y1) << 16) | f2bf(y0);
      if (j2 < 4) php0[j2] = hw; else php1[j2-4] = hw;
    }
    *(uint4*)(Yh + (size_t)g*128 + sg*16)     = ph0;
    *(uint4*)(Yh + (size_t)g*128 + sg*16 + 8) = ph1;
  }
}

// ================= layer-2 aggregation: ONE-PASS gather of h1 rows =================
#define ACC8(W_, U_) \
  tmp[0] = fmaf(W_, __uint_as_float((U_).x << 16),         tmp[0]); \
  tmp[1] = fmaf(W_, __uint_as_float((U_).x & 0xffff0000u), tmp[1]); \
  tmp[2] = fmaf(W_, __uint_as_float((U_).y << 16),         tmp[2]); \
  tmp[3] = fmaf(W_, __uint_as_float((U_).y & 0xffff0000u), tmp[3]); \
  tmp[4] = fmaf(W_, __uint_as_float((U_).z << 16),         tmp[4]); \
  tmp[5] = fmaf(W_, __uint_as_float((U_).z & 0xffff0000u), tmp[5]); \
  tmp[6] = fmaf(W_, __uint_as_float((U_).w << 16),         tmp[6]); \
  tmp[7] = fmaf(W_, __uint_as_float((U_).w & 0xffff0000u), tmp[7]);

__global__ void k_agg2(const unsigned short* __restrict__ h1,
                       const float* __restrict__ zsd,     // [12][n]
                       const int* __restrict__ elist,
                       const int* __restrict__ off,       // pre-offset by rbase*NN
                       int rbase,
                       unsigned short* __restrict__ agg2, // [3][n][128] bf16
                       int n)
{
  int gid = blockIdx.x*256 + threadIdx.x;
  int g = gid >> 4;
  int l = threadIdx.x & 15;
  int gbase = threadIdx.x & 48;
  if (g >= n) return;

  for (int r = 0; r < 3; ++r) {
    int o0 = off[(size_t)r*NN + g], o1 = off[(size_t)r*NN + g + 1];
    int deg = o1 - o0;
    float tmp[8] = {0,0,0,0,0,0,0,0};
    float inv = 0.f;
    if (deg > 0) {
      const float* zsr = zsd + (size_t)(rbase+r)*n;
      float zdd = zsd[(size_t)(6+rbase+r)*n + g];
      float esum = 0.f;
      for (int base = 0; base < deg; base += 16) {
        int i = base + l;
        float ew = 0.f; int s = 0;
        if (i < deg) {
          s = elist[o0+i];
          ew = wexp(zsr[s] + zdd);
        }
        esum += ew;
        int cnt = min(16, deg - base);
        for (int t = 0; t < cnt; t += 4) {
          float w0 = __shfl(ew, gbase + t);
          float w1 = __shfl(ew, gbase + t + 1);
          float w2 = __shfl(ew, gbase + t + 2);
          float w3 = __shfl(ew, gbase + t + 3);
          int a0 = __shfl(s, gbase + t);
          int a1 = __shfl(s, gbase + t + 1);
          int a2 = __shfl(s, gbase + t + 2);
          int a3 = __shfl(s, gbase + t + 3);
          uint4 u0 = *(const uint4*)(h1 + (size_t)a0*128 + l*8);
          uint4 u1 = *(const uint4*)(h1 + (size_t)a1*128 + l*8);
          uint4 u2 = *(const uint4*)(h1 + (size_t)a2*128 + l*8);
          uint4 u3 = *(const uint4*)(h1 + (size_t)a3*128 + l*8);
          ACC8(w0, u0);
          ACC8(w1, u1);
          ACC8(w2, u2);
          ACC8(w3, u3);
        }
      }
      esum += __shfl_xor(esum, 1);
      esum += __shfl_xor(esum, 2);
      esum += __shfl_xor(esum, 4);
      esum += __shfl_xor(esum, 8);
      inv = 1.f / esum;
    }
    uint4 ph;
    unsigned* php = (unsigned*)&ph;
    #pragma unroll
    for (int j2 = 0; j2 < 4; ++j2) {
      float a0 = tmp[2*j2]   * inv;
      float a1 = tmp[2*j2+1] * inv;
      php[j2] = ((unsigned)f2bf(a1) << 16) | f2bf(a0);
    }
    *(uint4*)(agg2 + ((size_t)r*n + g)*128 + l*8) = ph;
  }
}

// ================= layer-2 concat-GEMM v3 (proven r13: fragment-layout W) ======
template<int FIN>
__global__ __launch_bounds__(512, 2)
void k_gemm2(const unsigned short* __restrict__ agg2,   // [3][n][128] bf16
             const short* __restrict__ WhAll, const short* __restrict__ WlAll, int rbase,
             const float* __restrict__ bsv,
             const float* __restrict__ nw, const float* __restrict__ nb,
             float* __restrict__ hacc, float* __restrict__ Yf,
             const float* __restrict__ q, const int* __restrict__ batch,
             float* __restrict__ scores, unsigned* __restrict__ bmax, int n)
{
  constexpr int KP = 128;
  __shared__ __align__(16) short lds[2*128*KP];   // Wh frag + Wl frag = 64 KB
  constexpr int WH0 = 0, WL0 = 128*KP;
  int tid = threadIdx.x;
  int r0 = blockIdx.x * 128;
  int wid = tid >> 6, lane = tid & 63;
  int lr = lane & 15, lg = lane >> 4;
  int grow = r0 + wid*16 + lr;
  int growc = min(grow, n-1);
  f32x4 acc[8] = {{0,0,0,0},{0,0,0,0},{0,0,0,0},{0,0,0,0},
                  {0,0,0,0},{0,0,0,0},{0,0,0,0},{0,0,0,0}};

  for (int rel = 0; rel < 3; ++rel) {
    const short* Ar = (const short*)(agg2 + (size_t)rel*n*KP);
    const short* Wh = WhAll + (size_t)(rbase+rel)*128*KP;
    const short* Wl = WlAll + (size_t)(rbase+rel)*128*KP;
    for (int ch = tid; ch < 128*16; ch += 512) {
      *(bf16x8*)(lds + WH0 + ch*8) = *(const bf16x8*)(Wh + (size_t)ch*8);
      *(bf16x8*)(lds + WL0 + ch*8) = *(const bf16x8*)(Wl + (size_t)ch*8);
    }
    __syncthreads();
    #pragma unroll
    for (int kc = 0; kc < 4; ++kc) {
      int kb = kc*32 + 4*lg;
      bf16x8 ah = ldfragG(Ar, growc, kb, KP);
      int fbase = ((kc*4 + lg)*128)*8;
      #pragma unroll
      for (int ct = 0; ct < 8; ++ct) {
        int wrow = ct*16 + lr;
        bf16x8 wh = *(const bf16x8*)(lds + WH0 + fbase + wrow*8);
        bf16x8 wl = *(const bf16x8*)(lds + WL0 + fbase + wrow*8);
        acc[ct] = __builtin_amdgcn_mfma_f32_16x16x32_bf16(ah, wh, acc[ct], 0, 0, 0);
        acc[ct] = __builtin_amdgcn_mfma_f32_16x16x32_bf16(ah, wl, acc[ct], 0, 0, 0);
      }
    }
    __syncthreads();
  }

  if (FIN == 0) {
    #pragma unroll
    for (int v = 0; v < 4; ++v) {
      int row = r0 + wid*16 + lg*4 + v;
      if (row < n) {
        #pragma unroll
        for (int ct = 0; ct < 8; ++ct)
          hacc[(size_t)row*128 + ct*16 + lr] = acc[ct][v];
      }
    }
  } else {
    #pragma unroll
    for (int v = 0; v < 4; ++v) {
      int row = r0 + wid*16 + lg*4 + v;
      int rowc = min(row, n-1);
      float vals[8];
      float s = 0.f;
      #pragma unroll
      for (int ct = 0; ct < 8; ++ct) {
        int c = ct*16 + lr;
        float x = acc[ct][v] + hacc[(size_t)rowc*128 + c] + bsv[c];
        x = 0.5f*x*(1.f + erff(x*0.70710678118654752f));
        vals[ct] = x;
        s += x;
      }
      s += __shfl_xor(s, 1); s += __shfl_xor(s, 2);
      s += __shfl_xor(s, 4); s += __shfl_xor(s, 8);
      float mu = s * (1.f/128.f);
      float var = 0.f;
      #pragma unroll
      for (int ct = 0; ct < 8; ++ct) { vals[ct] -= mu; var += vals[ct]*vals[ct]; }
      var += __shfl_xor(var, 1); var += __shfl_xor(var, 2);
      var += __shfl_xor(var, 4); var += __shfl_xor(var, 8);
      float inv = 1.f / sqrtf(var*(1.f/128.f) + 1e-5f);
      float sc = 0.f;
      #pragma unroll
      for (int ct = 0; ct < 8; ++ct) {
        int c = ct*16 + lr;
        float y = vals[ct]*inv*nw[c] + nb[c];
        if (row < n) Yf[(size_t)row*128 + c] = y;
        sc = fmaf(y, q[c], sc);
      }
      sc += __shfl_xor(sc, 1); sc += __shfl_xor(sc, 2);
      sc += __shfl_xor(sc, 4); sc += __shfl_xor(sc, 8);
      if (lr == 0 && row < n) {
        scores[row] = sc;
        atomicMax(&bmax[batch[row]], fenc(sc));
      }
    }
  }
}

// ================= bias-sum =================
__global__ void k_bsum(const float* __restrict__ b, float* __restrict__ bs)
{
  int t = threadIdx.x;
  float s = 0.f;
  #pragma unroll
  for (int r = 0; r < RR; ++r) s += b[r*HH + t];
  bs[t] = s;
}

// ================= pooling =================
__global__ void k_segbounds(const int* __restrict__ batch, int* __restrict__ segst,
                            int n, int numB)
{
  int b = blockIdx.x*256 + threadIdx.x;
  if (b > numB) return;
  int lo = 0, hi = n;
  while (lo < hi) { int mid = (lo+hi) >> 1; if (batch[mid] < b) lo = mid+1; else hi = mid; }
  segst[b] = lo;
}

__global__ void k_pool(const float* __restrict__ X, const float* __restrict__ scores,
                       const int* __restrict__ segst, const unsigned* __restrict__ bmax,
                       float* __restrict__ pool, int numB)
{
  int b = blockIdx.x;
  int t = threadIdx.x;
  int s0 = segst[b], s1 = segst[b+1];
  float m = fdec(bmax[b]);
  float acc0 = 0.f, acc1 = 0.f, esum = 0.f;
  int i = s0;
  for (; i + 1 < s1; i += 2) {
    float e0 = __expf(scores[i] - m);
    float e1 = __expf(scores[i+1] - m);
    esum += e0 + e1;
    acc0 = fmaf(e0, X[(size_t)i*128 + t], acc0);
    acc1 = fmaf(e1, X[(size_t)(i+1)*128 + t], acc1);
  }
  if (i < s1) {
    float e0 = __expf(scores[i] - m);
    esum += e0;
    acc0 = fmaf(e0, X[(size_t)i*128 + t], acc0);
  }
  float inv = (s1 > s0) ? 1.f/esum : 0.f;
  pool[(size_t)b*128 + t] = (acc0 + acc1) * inv;
}

__global__ void k_outgemm(const float* __restrict__ pool, const float* __restrict__ projW,
                          const float* __restrict__ projb, float* __restrict__ out, int numB)
{
  int b = blockIdx.x;
  int j = threadIdx.x;
  __shared__ float p[128];
  p[j] = pool[(size_t)b*128 + j];
  __syncthreads();
  float acc = projb[j];
  #pragma unroll 16
  for (int k = 0; k < 128; ++k) acc = fmaf(p[k], projW[(size_t)k*128 + j], acc);
  out[(size_t)b*128 + j] = acc;
}

// ================= launcher =================
extern "C" void kernel_launch(void* const* d_in, const int* in_sizes, int n_in,
                              void* d_out, int out_size, void* d_ws, size_t ws_size,
                              hipStream_t stream)
{
  const float* x_all = (const float*)d_in[0];
  const int*   edges = (const int*)d_in[1];
  const int*   batch = (const int*)d_in[2];
  const float* pos_table = (const float*)d_in[3];
  const float* W1  = (const float*)d_in[4];
  const float* as1 = (const float*)d_in[5];
  const float* ad1 = (const float*)d_in[6];
  const float* b1  = (const float*)d_in[7];
  const float* W2  = (const float*)d_in[8];
  const float* as2 = (const float*)d_in[9];
  const float* ad2 = (const float*)d_in[10];
  const float* b2  = (const float*)d_in[11];
  const float* n1w = (const float*)d_in[12];
  const float* n1b = (const float*)d_in[13];
  const float* n2w = (const float*)d_in[14];
  const float* n2b = (const float*)d_in[15];
  const float* query = (const float*)d_in[16];
  const float* projW = (const float*)d_in[17];
  const float* projb = (const float*)d_in[18];
  float* out = (float*)d_out;
  (void)in_sizes; (void)n_in; (void)out_size; (void)ws_size;

  char* p = (char*)d_ws;
  auto alloc = [&](size_t b){ void* r = (void*)p; p += (b + 255) & ~(size_t)255; return r; };
  int*   off   = (int*)alloc((size_t)(MM+1)*sizeof(int));
  int*   elist = (int*)alloc((size_t)RR*EE*sizeof(int));
  int*   boff  = (int*)alloc((size_t)(NBK+1)*sizeof(int));
  int*   bcur  = (int*)alloc((size_t)NBK*sizeof(int));
  short* wtH   = (short*)alloc((size_t)RR*128*128*sizeof(short));
  short* wtL   = (short*)alloc((size_t)RR*128*128*sizeof(short));
  float* wa    = (float*)alloc((size_t)12*128*sizeof(float));
  float* zsd   = (float*)alloc((size_t)12*NN*sizeof(float));
  float* bsv   = (float*)alloc(128*sizeof(float));
  int*   segst = (int*)alloc((size_t)(BB+1)*sizeof(int));
  unsigned* bmax = (unsigned*)alloc((size_t)BB*sizeof(unsigned));
  float* pool  = (float*)alloc((size_t)BB*HH*sizeof(float));
  float* scrs  = (float*)alloc((size_t)NN*sizeof(float));
  unsigned short* big = (unsigned short*)alloc((size_t)3*NN*128*sizeof(short)); // aggH, agg2
  float* R1    = (float*)alloc((size_t)NN*128*sizeof(float));  // ebkt -> x0 -> hacc
  float* R2    = (float*)alloc((size_t)NN*128*sizeof(float));  // h1h (bf16) -> h2 (f32)

  unsigned* ebkt = (unsigned*)R1;
  short* x0h = (short*)R1;
  short* x0l = x0h + (size_t)NN*32;
  float* hacc = R1;
  unsigned short* h1h = (unsigned short*)R2;
  float* h2 = (float*)R2;
  unsigned short* aggH = big;                  // [6][N][32]
  unsigned short* agg2 = big;                  // [3][N][128] (after gemm1)

  // --- CSR build ---
  const int nch = (EE + CH - 1) / CH;
  hipMemsetAsync(bcur, 0, (size_t)NBK*sizeof(int), stream);
  k_binscatter<<<RR*nch,256,0,stream>>>(edges, bcur, ebkt);
  k_bscan<<<1,256,0,stream>>>(bcur, boff, off);
  k_bbuild<<<NBK,256,0,stream>>>(ebkt, bcur, boff, off, elist);

  // --- prep ---
  k_featprep<<<ceil_div(NN*32,256),256,0,stream>>>(x_all, pos_table, x0h, x0l);
  k_segbounds<<<ceil_div(BB+1,256),256,0,stream>>>(batch, segst, NN, BB);
  hipMemsetAsync(bmax, 0, (size_t)BB*sizeof(unsigned), stream);

  // --- layer 1 ---
  k_wa<32><<<ceil_div(12*32,256),256,0,stream>>>(W1, as1, ad1, 21, wa);
  k_zsd32<<<ceil_div(NN,256),256,0,stream>>>(x0h, x0l, wa, zsd, NN);
  k_wprep<32><<<ceil_div(RR*128*32,256),256,0,stream>>>(W1, 21, wtH, wtL);
  k_bsum<<<1,128,0,stream>>>(b1, bsv);
  k_agg1<<<ceil_div(NN*16,256),256,0,stream>>>((const unsigned short*)x0h, zsd, elist, off,
                                               aggH, NN);
  k_gemm1<<<ceil_div(NN,32),256,0,stream>>>((const short*)aggH,
                                            wtH, wtL, bsv, n1w, n1b, h1h, NN);

  // --- layer 2 ---
  k_wa<128><<<ceil_div(12*128,256),256,0,stream>>>(W2, as2, ad2, 128, wa);
  k_zsd128<<<ceil_div(NN*16,256),256,0,stream>>>(h1h, wa, zsd, NN);
  k_wprep2<<<ceil_div(RR*128*128,256),256,0,stream>>>(W2, wtH, wtL);
  k_bsum<<<1,128,0,stream>>>(b2, bsv);
  int aggGrid = ceil_div(NN*16, 256);
  int gemm2Grid = ceil_div(NN, 128);
  k_agg2<<<aggGrid,256,0,stream>>>(h1h, zsd, elist, off, 0, agg2, NN);
  k_gemm2<0><<<gemm2Grid,512,0,stream>>>(agg2, wtH, wtL, 0, bsv, n2w, n2b,
      hacc, (float*)0, query, batch, scrs, bmax, NN);
  k_agg2<<<aggGrid,256,0,stream>>>(h1h, zsd, elist, off + (size_t)3*NN, 3, agg2, NN);
  k_gemm2<1><<<gemm2Grid,512,0,stream>>>(agg2, wtH, wtL, 3, bsv, n2w, n2b,
      hacc, h2, query, batch, scrs, bmax, NN);

  // --- attention pooling ---
  k_pool<<<BB,128,0,stream>>>(h2, scrs, segst, bmax, pool, BB);
  k_outgemm<<<BB,128,0,stream>>>(pool, projW, projb, out, BB);
}